// Round 1
// baseline (506.192 us; speedup 1.0000x reference)
//
#include <hip/hip_runtime.h>
#include <hip/hip_bf16.h>

// MQA: B=2, S=2048, H=2048, NH=16, D=128
#define NB 2
#define NS 2048
#define NHID 2048
#define NHEAD 16
#define ND 128
#define NM (NB*NS)   // 4096

typedef __attribute__((ext_vector_type(8))) short s16x8;
typedef __attribute__((ext_vector_type(4))) float f32x4;

__device__ __forceinline__ short f2bf(float x) {
  unsigned u = __float_as_uint(x);
  u = (u + 0x7fffu + ((u >> 16) & 1u)) >> 16;
  return (short)u;
}

__device__ __forceinline__ int colmap(int wc, int ni) {
  // frag ni in {0,1} -> cols [wc*32 + ni*16, +16) ; ni in {2,3} -> +64 partner
  return (ni < 2) ? (wc*32 + ni*16) : (64 + wc*32 + (ni-2)*16);
}

// ---------------- conversions ----------------
__global__ __launch_bounds__(256) void cvt_f32_bf16(const float* __restrict__ src,
                                                    short* __restrict__ dst, int n4) {
  int i = blockIdx.x*256 + threadIdx.x;
  if (i >= n4) return;
  const float4 v = reinterpret_cast<const float4*>(src)[i];
  unsigned long long pk =
      (unsigned long long)(unsigned short)f2bf(v.x)
    | ((unsigned long long)(unsigned short)f2bf(v.y) << 16)
    | ((unsigned long long)(unsigned short)f2bf(v.z) << 32)
    | ((unsigned long long)(unsigned short)f2bf(v.w) << 48);
  reinterpret_cast<unsigned long long*>(dst)[i] = pk;
}

// src [K][N] fp32 -> dst [N][K] bf16
__global__ __launch_bounds__(256) void cvtT(const float* __restrict__ src,
                                            short* __restrict__ dst, int K, int N) {
  __shared__ float t[32][33];
  const int n0 = blockIdx.x*32, k0 = blockIdx.y*32;
  const int tx = threadIdx.x & 31, ty = threadIdx.x >> 5;
  #pragma unroll
  for (int i = 0; i < 4; ++i)
    t[ty + 8*i][tx] = src[(size_t)(k0 + ty + 8*i)*N + n0 + tx];
  __syncthreads();
  #pragma unroll
  for (int i = 0; i < 4; ++i)
    dst[(size_t)(n0 + ty + 8*i)*K + k0 + tx] = f2bf(t[tx][ty + 8*i]);
}

// ---------------- GEMM1: QKV projection + RoPE epilogue ----------------
// grid (NM/128, 18): y<16 -> Q head y ; y==16 -> K ; y==17 -> V
__global__ __launch_bounds__(256) void gemm_qkv(
    const short* __restrict__ hsb, const short* __restrict__ WqT,
    const short* __restrict__ WkT, const short* __restrict__ WvT,
    const float* __restrict__ ropeC, const float* __restrict__ ropeS,
    short* __restrict__ Qb, short* __restrict__ Kb, short* __restrict__ Vb)
{
  const int tid = threadIdx.x;
  const int lane = tid & 63, wid = tid >> 6;
  const int wr = wid >> 1, wc = wid & 1;
  const int l15 = lane & 15, l4 = lane >> 4;
  const int m0 = blockIdx.x * 128;
  const int ny = blockIdx.y;
  const short* Bt = (ny < 16) ? (WqT + (size_t)ny*128*2048) : (ny == 16 ? WkT : WvT);

  __shared__ short Al[128][40];   // +8 pad: conflict-light frag reads
  __shared__ short Bl[128][40];

  f32x4 acc[4][4];
  const f32x4 zf = {0.f,0.f,0.f,0.f};
  #pragma unroll
  for (int i=0;i<4;++i)
    #pragma unroll
    for (int j=0;j<4;++j) acc[i][j] = zf;

  const int srow = tid >> 2;
  const int skoff = (tid & 3) * 8;
  const short* Ap = hsb + (size_t)(m0 + srow)*2048 + skoff;
  const short* Bp = Bt + (size_t)srow*2048 + skoff;

  for (int kt = 0; kt < 64; ++kt) {
    const int k0 = kt * 32;
    uint4 a0 = *(const uint4*)(Ap + k0);
    uint4 a1 = *(const uint4*)(Ap + 64*2048 + k0);
    uint4 b0 = *(const uint4*)(Bp + k0);
    uint4 b1 = *(const uint4*)(Bp + 64*2048 + k0);
    __syncthreads();
    *(uint4*)&Al[srow][skoff]    = a0;
    *(uint4*)&Al[srow+64][skoff] = a1;
    *(uint4*)&Bl[srow][skoff]    = b0;
    *(uint4*)&Bl[srow+64][skoff] = b1;
    __syncthreads();
    s16x8 af[4], bfr[4];
    #pragma unroll
    for (int mi=0; mi<4; ++mi) af[mi] = *(const s16x8*)&Al[wr*64 + mi*16 + l15][l4*8];
    #pragma unroll
    for (int ni=0; ni<4; ++ni) bfr[ni] = *(const s16x8*)&Bl[colmap(wc,ni) + l15][l4*8];
    #pragma unroll
    for (int mi=0; mi<4; ++mi)
      #pragma unroll
      for (int ni=0; ni<4; ++ni)
        acc[mi][ni] = __builtin_amdgcn_mfma_f32_16x16x32_bf16(af[mi], bfr[ni], acc[mi][ni], 0,0,0);
  }

  const bool isQ = (ny < 16), isK = (ny == 16);
  #pragma unroll
  for (int mi=0; mi<4; ++mi) {
    #pragma unroll
    for (int r=0; r<4; ++r) {
      const int mrow = m0 + wr*64 + mi*16 + l4*4 + r;
      const int s = mrow & 2047;
      const int bb = mrow >> 11;
      if (!isQ && !isK) {           // V: no rope
        #pragma unroll
        for (int ni=0; ni<4; ++ni) {
          const int d = colmap(wc,ni) + l15;
          Vb[(size_t)mrow*128 + d] = f2bf(acc[mi][ni][r]);
        }
      } else {                      // Q/K: rope, partner frag ni+2 holds col d+64
        #pragma unroll
        for (int ni=0; ni<2; ++ni) {
          const int d = colmap(wc,ni) + l15;     // in [0,64)
          const float c0 = ropeC[s*128 + d],      s0 = ropeS[s*128 + d];
          const float c1 = ropeC[s*128 + d + 64], s1 = ropeS[s*128 + d + 64];
          const float x0 = acc[mi][ni][r], x1 = acc[mi][ni+2][r];
          const float y0 = x0*c0 - x1*s0;
          const float y1 = x1*c1 + x0*s1;
          if (isK) {
            Kb[(size_t)mrow*128 + d]      = f2bf(y0);
            Kb[(size_t)mrow*128 + d + 64] = f2bf(y1);
          } else {
            const size_t base = ((size_t)(bb*16 + ny)*2048 + s)*128;
            Qb[base + d]      = f2bf(y0);
            Qb[base + d + 64] = f2bf(y1);
          }
        }
      }
    }
  }
}

// ---------------- flash attention (causal, MQA) ----------------
// grid (S/64, NH, B), 4 waves; wave w owns Q rows [q0+16w, q0+16w+16)
__global__ __launch_bounds__(256) void attn_fwd(
    const short* __restrict__ Qb, const short* __restrict__ Kb,
    const short* __restrict__ Vb, short* __restrict__ Ob)
{
  const int tid = threadIdx.x;
  const int lane = tid & 63, wid = tid >> 6;
  const int l15 = lane & 15, l4 = lane >> 4;
  const int qt = blockIdx.x, h = blockIdx.y, b = blockIdx.z;
  const int q0 = qt * 64;

  __shared__ short Kl[64][136];    // K tile, +8 pad
  __shared__ short Vt[128][72];    // V^T tile, +8 pad
  __shared__ short Pl[4][16][72];  // per-wave P, +8 pad

  s16x8 qf[4];
  {
    const short* Qp = Qb + ((size_t)(b*16 + h)*2048 + q0 + wid*16 + l15)*128 + l4*8;
    #pragma unroll
    for (int kk=0; kk<4; ++kk) qf[kk] = *(const s16x8*)(Qp + kk*32);
  }

  float m_run[4], l_run[4];
  f32x4 o[8];
  const f32x4 zf = {0.f,0.f,0.f,0.f};
  #pragma unroll
  for (int r=0;r<4;++r){ m_run[r] = -1e30f; l_run[r] = 0.f; }
  #pragma unroll
  for (int i=0;i<8;++i) o[i] = zf;

  const float CEXP = 0.08838834764831845f * 1.44269504088896340f;

  const int ntiles = qt + 1;
  for (int t=0; t<ntiles; ++t) {
    const int kv0 = t*64;
    __syncthreads();
    #pragma unroll
    for (int rep=0; rep<4; ++rep) {
      const int c = tid + rep*256;
      { // K: linear rows
        const int row = c >> 4, off = (c & 15) * 8;
        *(uint4*)&Kl[row][off] = *(const uint4*)(Kb + ((size_t)(b*2048 + kv0 + row))*128 + off);
      }
      { // V: transpose-store, lane-per-row to spread banks
        const int row = c & 63, off = (c >> 6) * 8;
        uint4 vv = *(const uint4*)(Vb + ((size_t)(b*2048 + kv0 + row))*128 + off);
        const short* vs = (const short*)&vv;
        #pragma unroll
        for (int j=0;j<8;++j) Vt[off + j][row] = vs[j];
      }
    }
    __syncthreads();

    // S = Q K^T  (16x64 per wave)
    f32x4 sc[4];
    #pragma unroll
    for (int n=0;n<4;++n) sc[n] = zf;
    #pragma unroll
    for (int kk=0; kk<4; ++kk) {
      #pragma unroll
      for (int n=0; n<4; ++n) {
        s16x8 kf = *(const s16x8*)&Kl[n*16 + l15][kk*32 + l4*8];
        sc[n] = __builtin_amdgcn_mfma_f32_16x16x32_bf16(qf[kk], kf, sc[n], 0,0,0);
      }
    }

    float p[4][4];
    const bool diag = (t == ntiles-1);
    #pragma unroll
    for (int n=0;n<4;++n)
      #pragma unroll
      for (int r=0;r<4;++r) {
        float sv = sc[n][r];
        if (diag) {
          const int qg  = wid*16 + l4*4 + r;
          const int kvg = n*16 + l15;
          if (kvg > qg) sv = -1e30f;
        }
        p[n][r] = sv;
      }
    // row max over the 16-lane group
    float pm[4];
    #pragma unroll
    for (int r=0;r<4;++r)
      pm[r] = fmaxf(fmaxf(p[0][r], p[1][r]), fmaxf(p[2][r], p[3][r]));
    #pragma unroll
    for (int d=1; d<16; d<<=1)
      #pragma unroll
      for (int r=0;r<4;++r) pm[r] = fmaxf(pm[r], __shfl_xor(pm[r], d));
    float alpha[4];
    #pragma unroll
    for (int r=0;r<4;++r) {
      const float mn = fmaxf(m_run[r], pm[r]);
      alpha[r] = exp2f((m_run[r] - mn) * CEXP);
      m_run[r] = mn;
    }
    #pragma unroll
    for (int n=0;n<4;++n)
      #pragma unroll
      for (int r=0;r<4;++r)
        p[n][r] = exp2f((p[n][r] - m_run[r]) * CEXP);
    float rs[4];
    #pragma unroll
    for (int r=0;r<4;++r) rs[r] = (p[0][r]+p[1][r])+(p[2][r]+p[3][r]);
    #pragma unroll
    for (int d=1; d<16; d<<=1)
      #pragma unroll
      for (int r=0;r<4;++r) rs[r] += __shfl_xor(rs[r], d);
    #pragma unroll
    for (int r=0;r<4;++r) l_run[r] = l_run[r]*alpha[r] + rs[r];
    #pragma unroll
    for (int i=0;i<8;++i)
      #pragma unroll
      for (int r=0;r<4;++r) o[i][r] *= alpha[r];

    // P -> LDS (bf16), then re-read as A-fragments
    #pragma unroll
    for (int n=0;n<4;++n)
      #pragma unroll
      for (int r=0;r<4;++r)
        Pl[wid][l4*4 + r][n*16 + l15] = f2bf(p[n][r]);
    __syncthreads();

    s16x8 pa[2];
    #pragma unroll
    for (int kb=0; kb<2; ++kb) pa[kb] = *(const s16x8*)&Pl[wid][l15][kb*32 + l4*8];
    #pragma unroll
    for (int kb=0; kb<2; ++kb)
      #pragma unroll
      for (int d8=0; d8<8; ++d8) {
        s16x8 vf = *(const s16x8*)&Vt[d8*16 + l15][kb*32 + l4*8];
        o[d8] = __builtin_amdgcn_mfma_f32_16x16x32_bf16(pa[kb], vf, o[d8], 0,0,0);
      }
  }

  #pragma unroll
  for (int r=0;r<4;++r) {
    const float inv = 1.0f / l_run[r];
    const size_t base = ((size_t)(b*2048) + q0 + wid*16 + l4*4 + r)*2048 + (size_t)h*128;
    #pragma unroll
    for (int d8=0; d8<8; ++d8)
      Ob[base + d8*16 + l15] = f2bf(o[d8][r] * inv);
  }
}

// ---------------- GEMM2: O @ Wo -> fp32 out ----------------
__global__ __launch_bounds__(256) void gemm_out(
    const short* __restrict__ Ob, const short* __restrict__ WoT,
    float* __restrict__ out)
{
  const int tid = threadIdx.x;
  const int lane = tid & 63, wid = tid >> 6;
  const int wr = wid >> 1, wc = wid & 1;
  const int l15 = lane & 15, l4 = lane >> 4;
  const int m0 = blockIdx.x * 128;
  const int n0 = blockIdx.y * 128;

  __shared__ short Al[128][40];
  __shared__ short Bl[128][40];

  f32x4 acc[4][4];
  const f32x4 zf = {0.f,0.f,0.f,0.f};
  #pragma unroll
  for (int i=0;i<4;++i)
    #pragma unroll
    for (int j=0;j<4;++j) acc[i][j] = zf;

  const int srow = tid >> 2;
  const int skoff = (tid & 3) * 8;
  const short* Ap = Ob + (size_t)(m0 + srow)*2048 + skoff;
  const short* Bp = WoT + (size_t)(n0 + srow)*2048 + skoff;

  for (int kt = 0; kt < 64; ++kt) {
    const int k0 = kt * 32;
    uint4 a0 = *(const uint4*)(Ap + k0);
    uint4 a1 = *(const uint4*)(Ap + 64*2048 + k0);
    uint4 b0 = *(const uint4*)(Bp + k0);
    uint4 b1 = *(const uint4*)(Bp + 64*2048 + k0);
    __syncthreads();
    *(uint4*)&Al[srow][skoff]    = a0;
    *(uint4*)&Al[srow+64][skoff] = a1;
    *(uint4*)&Bl[srow][skoff]    = b0;
    *(uint4*)&Bl[srow+64][skoff] = b1;
    __syncthreads();
    s16x8 af[4], bfr[4];
    #pragma unroll
    for (int mi=0; mi<4; ++mi) af[mi] = *(const s16x8*)&Al[wr*64 + mi*16 + l15][l4*8];
    #pragma unroll
    for (int ni=0; ni<4; ++ni) bfr[ni] = *(const s16x8*)&Bl[colmap(wc,ni) + l15][l4*8];
    #pragma unroll
    for (int mi=0; mi<4; ++mi)
      #pragma unroll
      for (int ni=0; ni<4; ++ni)
        acc[mi][ni] = __builtin_amdgcn_mfma_f32_16x16x32_bf16(af[mi], bfr[ni], acc[mi][ni], 0,0,0);
  }

  #pragma unroll
  for (int mi=0; mi<4; ++mi)
    #pragma unroll
    for (int r=0; r<4; ++r) {
      const int mrow = m0 + wr*64 + mi*16 + l4*4 + r;
      #pragma unroll
      for (int ni=0; ni<4; ++ni)
        out[(size_t)mrow*2048 + n0 + colmap(wc,ni) + l15] = acc[mi][ni][r];
    }
}

// ---------------- launch ----------------
extern "C" void kernel_launch(void* const* d_in, const int* in_sizes, int n_in,
                              void* d_out, int out_size, void* d_ws, size_t ws_size,
                              hipStream_t stream) {
  const float* hidden = (const float*)d_in[0];
  // d_in[1] attention_mask: exactly causal -> implemented analytically
  const float* ropeC  = (const float*)d_in[2];
  const float* ropeS  = (const float*)d_in[3];
  const float* Wq     = (const float*)d_in[4];
  const float* Wk     = (const float*)d_in[5];
  const float* Wv     = (const float*)d_in[6];
  const float* Wo     = (const float*)d_in[7];
  float* out = (float*)d_out;
  char* ws = (char*)d_ws;

  // workspace layout (bytes); Ob aliases hsb (hsb dead after gemm_qkv)
  short* hsb = (short*)(ws + 0);                 // 16,777,216
  short* WqT = (short*)(ws + 16777216);          //  8,388,608
  short* WkT = (short*)(ws + 25165824);          //    524,288
  short* WvT = (short*)(ws + 25690112);          //    524,288
  short* WoT = (short*)(ws + 26214400);          //  8,388,608
  short* Qb  = (short*)(ws + 34603008);          // 16,777,216
  short* Kb  = (short*)(ws + 51380224);          //  1,048,576
  short* Vb  = (short*)(ws + 52428800);          //  1,048,576
  short* Ob  = hsb;                              // alias

  cvt_f32_bf16<<<dim3((NM*NHID/4 + 255)/256), dim3(256), 0, stream>>>(hidden, hsb, NM*NHID/4);
  cvtT<<<dim3(64,64), dim3(256), 0, stream>>>(Wq, WqT, 2048, 2048);
  cvtT<<<dim3(4, 64), dim3(256), 0, stream>>>(Wk, WkT, 2048, 128);
  cvtT<<<dim3(4, 64), dim3(256), 0, stream>>>(Wv, WvT, 2048, 128);
  cvtT<<<dim3(64,64), dim3(256), 0, stream>>>(Wo, WoT, 2048, 2048);

  gemm_qkv<<<dim3(NM/128, 18), dim3(256), 0, stream>>>(hsb, WqT, WkT, WvT, ropeC, ropeS, Qb, Kb, Vb);
  attn_fwd<<<dim3(NS/64, NHEAD, NB), dim3(256), 0, stream>>>(Qb, Kb, Vb, Ob);
  gemm_out<<<dim3(NM/128, 2048/128), dim3(256), 0, stream>>>(Ob, WoT, out);
}

// Round 2
// 461.820 us; speedup vs baseline: 1.0961x; 1.0961x over previous
//
#include <hip/hip_runtime.h>
#include <hip/hip_bf16.h>

// MQA: B=2, S=2048, H=2048, NH=16, D=128
#define NB 2
#define NS 2048
#define NHID 2048
#define NHEAD 16
#define ND 128
#define NM (NB*NS)   // 4096

typedef __attribute__((ext_vector_type(8))) short s16x8;
typedef __attribute__((ext_vector_type(4))) float f32x4;

__device__ __forceinline__ short f2bf(float x) {
  unsigned u = __float_as_uint(x);
  u = (u + 0x7fffu + ((u >> 16) & 1u)) >> 16;
  return (short)u;
}

__device__ __forceinline__ int colmap(int wc, int ni) {
  return (ni < 2) ? (wc*32 + ni*16) : (64 + wc*32 + (ni-2)*16);
}

__device__ __forceinline__ void gload16(const short* g, short* l) {
  __builtin_amdgcn_global_load_lds(
      (const __attribute__((address_space(1))) void*)g,
      (__attribute__((address_space(3))) void*)l, 16, 0, 0);
}

// ---------------- conversions ----------------
__global__ __launch_bounds__(256) void cvt_f32_bf16(const float* __restrict__ src,
                                                    short* __restrict__ dst, int n4) {
  int i = blockIdx.x*256 + threadIdx.x;
  if (i >= n4) return;
  const float4 v = reinterpret_cast<const float4*>(src)[i];
  unsigned long long pk =
      (unsigned long long)(unsigned short)f2bf(v.x)
    | ((unsigned long long)(unsigned short)f2bf(v.y) << 16)
    | ((unsigned long long)(unsigned short)f2bf(v.z) << 32)
    | ((unsigned long long)(unsigned short)f2bf(v.w) << 48);
  reinterpret_cast<unsigned long long*>(dst)[i] = pk;
}

// src [K][N] fp32 -> dst [N][K] bf16
__global__ __launch_bounds__(256) void cvtT(const float* __restrict__ src,
                                            short* __restrict__ dst, int K, int N) {
  __shared__ float t[32][33];
  const int n0 = blockIdx.x*32, k0 = blockIdx.y*32;
  const int tx = threadIdx.x & 31, ty = threadIdx.x >> 5;
  #pragma unroll
  for (int i = 0; i < 4; ++i)
    t[ty + 8*i][tx] = src[(size_t)(k0 + ty + 8*i)*N + n0 + tx];
  __syncthreads();
  #pragma unroll
  for (int i = 0; i < 4; ++i)
    dst[(size_t)(n0 + ty + 8*i)*K + k0 + tx] = f2bf(t[tx][ty + 8*i]);
}

// ---------------- GEMM1: QKV projection + RoPE epilogue ----------------
// grid (NM/128, 18): y<16 -> Q head y ; y==16 -> K ; y==17 -> V
__global__ __launch_bounds__(256) void gemm_qkv(
    const short* __restrict__ hsb, const short* __restrict__ WqT,
    const short* __restrict__ WkT, const short* __restrict__ WvT,
    const float* __restrict__ ropeC, const float* __restrict__ ropeS,
    short* __restrict__ Qb, short* __restrict__ Kb, short* __restrict__ Vb)
{
  const int tid = threadIdx.x;
  const int lane = tid & 63, wid = tid >> 6;
  const int wr = wid >> 1, wc = wid & 1;
  const int l15 = lane & 15, l4 = lane >> 4;
  const int m0 = blockIdx.x * 128;
  const int ny = blockIdx.y;
  const short* Bt = (ny < 16) ? (WqT + (size_t)ny*128*2048) : (ny == 16 ? WkT : WvT);

  __shared__ short Al[128][32];
  __shared__ short Bl[128][32];

  f32x4 acc[4][4];
  const f32x4 zf = {0.f,0.f,0.f,0.f};
  #pragma unroll
  for (int i=0;i<4;++i)
    #pragma unroll
    for (int j=0;j<4;++j) acc[i][j] = zf;

  const int srow = tid >> 2;          // 0..63
  const int scol = (tid & 3) * 8;     // 0,8,16,24
  const short* Ap0 = hsb + (size_t)(m0 + srow)*2048 + scol;
  const short* Ap1 = hsb + (size_t)(m0 + 64 + srow)*2048 + scol;
  const short* Bp0 = Bt + (size_t)srow*2048 + scol;
  const short* Bp1 = Bt + (size_t)(64 + srow)*2048 + scol;
  short* AL0 = &Al[0][0] + tid*8;
  short* AL1 = &Al[0][0] + 2048 + tid*8;
  short* BL0 = &Bl[0][0] + tid*8;
  short* BL1 = &Bl[0][0] + 2048 + tid*8;

  for (int kt = 0; kt < 64; ++kt) {
    const int k0 = kt * 32;
    __syncthreads();
    gload16(Ap0 + k0, AL0);
    gload16(Ap1 + k0, AL1);
    gload16(Bp0 + k0, BL0);
    gload16(Bp1 + k0, BL1);
    __syncthreads();
    s16x8 af[4], bfr[4];
    #pragma unroll
    for (int mi=0; mi<4; ++mi) af[mi] = *(const s16x8*)&Al[wr*64 + mi*16 + l15][l4*8];
    #pragma unroll
    for (int ni=0; ni<4; ++ni) bfr[ni] = *(const s16x8*)&Bl[colmap(wc,ni) + l15][l4*8];
    #pragma unroll
    for (int mi=0; mi<4; ++mi)
      #pragma unroll
      for (int ni=0; ni<4; ++ni)
        acc[mi][ni] = __builtin_amdgcn_mfma_f32_16x16x32_bf16(af[mi], bfr[ni], acc[mi][ni], 0,0,0);
  }

  const bool isQ = (ny < 16), isK = (ny == 16);
  #pragma unroll
  for (int mi=0; mi<4; ++mi) {
    #pragma unroll
    for (int r=0; r<4; ++r) {
      const int mrow = m0 + wr*64 + mi*16 + l4*4 + r;
      const int s = mrow & 2047;
      const int bb = mrow >> 11;
      if (!isQ && !isK) {           // V: no rope
        #pragma unroll
        for (int ni=0; ni<4; ++ni) {
          const int d = colmap(wc,ni) + l15;
          Vb[(size_t)mrow*128 + d] = f2bf(acc[mi][ni][r]);
        }
      } else {                      // Q/K: rope; frag ni+2 holds col d+64
        #pragma unroll
        for (int ni=0; ni<2; ++ni) {
          const int d = colmap(wc,ni) + l15;     // in [0,64)
          const float c0 = ropeC[s*128 + d],      s0 = ropeS[s*128 + d];
          const float c1 = ropeC[s*128 + d + 64], s1 = ropeS[s*128 + d + 64];
          const float x0 = acc[mi][ni][r], x1 = acc[mi][ni+2][r];
          const float y0 = x0*c0 - x1*s0;
          const float y1 = x1*c1 + x0*s1;
          if (isK) {
            Kb[(size_t)mrow*128 + d]      = f2bf(y0);
            Kb[(size_t)mrow*128 + d + 64] = f2bf(y1);
          } else {
            const size_t base = ((size_t)(bb*16 + ny)*2048 + s)*128;
            Qb[base + d]      = f2bf(y0);
            Qb[base + d + 64] = f2bf(y1);
          }
        }
      }
    }
  }
}

// ---------------- flash attention (causal, MQA, paired q-tiles) ----------------
__device__ __forceinline__ void attn_tile_proc(
    const s16x8 (&qf)[4], int qtile, int t, int wid, int l15, int l4,
    short (&Kl)[64][136], short (&Vt)[128][72], short (&Pl)[4][16][72],
    f32x4 (&o)[8], float (&m_run)[4], float (&l_run)[4])
{
  const float CEXP = 0.08838834764831845f * 1.44269504088896340f;
  const f32x4 zf = {0.f,0.f,0.f,0.f};
  f32x4 sc[4];
  #pragma unroll
  for (int n=0;n<4;++n) sc[n] = zf;
  #pragma unroll
  for (int kk=0; kk<4; ++kk) {
    #pragma unroll
    for (int n=0; n<4; ++n) {
      s16x8 kf = *(const s16x8*)&Kl[n*16 + l15][kk*32 + l4*8];
      sc[n] = __builtin_amdgcn_mfma_f32_16x16x32_bf16(qf[kk], kf, sc[n], 0,0,0);
    }
  }

  float p[4][4];
  const bool diag = (t == qtile);
  #pragma unroll
  for (int n=0;n<4;++n)
    #pragma unroll
    for (int r=0;r<4;++r) {
      float sv = sc[n][r];
      if (diag) {
        const int qg  = wid*16 + l4*4 + r;
        const int kvg = n*16 + l15;
        if (kvg > qg) sv = -1e30f;
      }
      p[n][r] = sv;
    }
  float pm[4];
  #pragma unroll
  for (int r=0;r<4;++r)
    pm[r] = fmaxf(fmaxf(p[0][r], p[1][r]), fmaxf(p[2][r], p[3][r]));
  #pragma unroll
  for (int d=1; d<16; d<<=1)
    #pragma unroll
    for (int r=0;r<4;++r) pm[r] = fmaxf(pm[r], __shfl_xor(pm[r], d));
  float alpha[4];
  #pragma unroll
  for (int r=0;r<4;++r) {
    const float mn = fmaxf(m_run[r], pm[r]);
    alpha[r] = exp2f((m_run[r] - mn) * CEXP);
    m_run[r] = mn;
  }
  #pragma unroll
  for (int n=0;n<4;++n)
    #pragma unroll
    for (int r=0;r<4;++r)
      p[n][r] = exp2f((p[n][r] - m_run[r]) * CEXP);
  float rs[4];
  #pragma unroll
  for (int r=0;r<4;++r) rs[r] = (p[0][r]+p[1][r])+(p[2][r]+p[3][r]);
  #pragma unroll
  for (int d=1; d<16; d<<=1)
    #pragma unroll
    for (int r=0;r<4;++r) rs[r] += __shfl_xor(rs[r], d);
  #pragma unroll
  for (int r=0;r<4;++r) l_run[r] = l_run[r]*alpha[r] + rs[r];
  #pragma unroll
  for (int i=0;i<8;++i)
    #pragma unroll
    for (int r=0;r<4;++r) o[i][r] *= alpha[r];

  // P -> per-wave LDS (no block barrier needed), re-read as A-fragments
  #pragma unroll
  for (int n=0;n<4;++n)
    #pragma unroll
    for (int r=0;r<4;++r)
      Pl[wid][l4*4 + r][n*16 + l15] = f2bf(p[n][r]);

  s16x8 pa[2];
  #pragma unroll
  for (int kb=0; kb<2; ++kb) pa[kb] = *(const s16x8*)&Pl[wid][l15][kb*32 + l4*8];
  #pragma unroll
  for (int kb=0; kb<2; ++kb)
    #pragma unroll
    for (int d8=0; d8<8; ++d8) {
      s16x8 vf = *(const s16x8*)&Vt[d8*16 + l15][kb*32 + l4*8];
      o[d8] = __builtin_amdgcn_mfma_f32_16x16x32_bf16(pa[kb], vf, o[d8], 0,0,0);
    }
}

// grid (16, NH, B): block p owns q-tiles lo=p and hi=31-p (uniform 33 passes)
__global__ __launch_bounds__(256) void attn_fwd(
    const short* __restrict__ Qb, const short* __restrict__ Kb,
    const short* __restrict__ Vb, short* __restrict__ Ob)
{
  const int tid = threadIdx.x;
  const int lane = tid & 63, wid = tid >> 6;
  const int l15 = lane & 15, l4 = lane >> 4;
  const int pr = blockIdx.x, h = blockIdx.y, b = blockIdx.z;
  const int lo = pr, hi = 31 - pr;

  __shared__ short Kl[64][136];    // +8 pad
  __shared__ short Vt[128][72];    // V^T, +8 pad
  __shared__ short Pl[4][16][72];  // per-wave P, +8 pad

  s16x8 qfL[4], qfH[4];
  {
    const short* QpL = Qb + ((size_t)(b*16 + h)*2048 + lo*64 + wid*16 + l15)*128 + l4*8;
    const short* QpH = Qb + ((size_t)(b*16 + h)*2048 + hi*64 + wid*16 + l15)*128 + l4*8;
    #pragma unroll
    for (int kk=0; kk<4; ++kk) { qfL[kk] = *(const s16x8*)(QpL + kk*32);
                                 qfH[kk] = *(const s16x8*)(QpH + kk*32); }
  }

  float mL[4], lL[4], mH[4], lH[4];
  f32x4 oL[8], oH[8];
  const f32x4 zf = {0.f,0.f,0.f,0.f};
  #pragma unroll
  for (int r=0;r<4;++r){ mL[r]=-1e30f; lL[r]=0.f; mH[r]=-1e30f; lH[r]=0.f; }
  #pragma unroll
  for (int i=0;i<8;++i){ oL[i]=zf; oH[i]=zf; }

  for (int t=0; t<=hi; ++t) {
    const int kv0 = t*64;
    __syncthreads();
    #pragma unroll
    for (int rep=0; rep<4; ++rep) {
      const int c = tid + rep*256;
      { // K: linear rows
        const int row = c >> 4, off = (c & 15) * 8;
        *(uint4*)&Kl[row][off] = *(const uint4*)(Kb + ((size_t)(b*2048 + kv0 + row))*128 + off);
      }
      { // V: transpose-store
        const int row = c & 63, off = (c >> 6) * 8;
        uint4 vv = *(const uint4*)(Vb + ((size_t)(b*2048 + kv0 + row))*128 + off);
        const short* vs = (const short*)&vv;
        #pragma unroll
        for (int j=0;j<8;++j) Vt[off + j][row] = vs[j];
      }
    }
    __syncthreads();

    attn_tile_proc(qfH, hi, t, wid, l15, l4, Kl, Vt, Pl, oH, mH, lH);
    if (t <= lo)
      attn_tile_proc(qfL, lo, t, wid, l15, l4, Kl, Vt, Pl, oL, mL, lL);
  }

  #pragma unroll
  for (int r=0;r<4;++r) {
    const float invL = 1.0f / lL[r];
    const float invH = 1.0f / lH[r];
    const size_t baseL = ((size_t)(b*2048) + lo*64 + wid*16 + l4*4 + r)*2048 + (size_t)h*128;
    const size_t baseH = ((size_t)(b*2048) + hi*64 + wid*16 + l4*4 + r)*2048 + (size_t)h*128;
    #pragma unroll
    for (int d8=0; d8<8; ++d8) {
      Ob[baseL + d8*16 + l15] = f2bf(oL[d8][r] * invL);
      Ob[baseH + d8*16 + l15] = f2bf(oH[d8][r] * invH);
    }
  }
}

// ---------------- GEMM2: O @ Wo -> fp32 out ----------------
__global__ __launch_bounds__(256) void gemm_out(
    const short* __restrict__ Ob, const short* __restrict__ WoT,
    float* __restrict__ out)
{
  const int tid = threadIdx.x;
  const int lane = tid & 63, wid = tid >> 6;
  const int wr = wid >> 1, wc = wid & 1;
  const int l15 = lane & 15, l4 = lane >> 4;
  const int m0 = blockIdx.x * 128;
  const int n0 = blockIdx.y * 128;

  __shared__ short Al[128][32];
  __shared__ short Bl[128][32];

  f32x4 acc[4][4];
  const f32x4 zf = {0.f,0.f,0.f,0.f};
  #pragma unroll
  for (int i=0;i<4;++i)
    #pragma unroll
    for (int j=0;j<4;++j) acc[i][j] = zf;

  const int srow = tid >> 2;
  const int scol = (tid & 3) * 8;
  const short* Ap0 = Ob + (size_t)(m0 + srow)*2048 + scol;
  const short* Ap1 = Ob + (size_t)(m0 + 64 + srow)*2048 + scol;
  const short* Bp0 = WoT + (size_t)(n0 + srow)*2048 + scol;
  const short* Bp1 = WoT + (size_t)(n0 + 64 + srow)*2048 + scol;
  short* AL0 = &Al[0][0] + tid*8;
  short* AL1 = &Al[0][0] + 2048 + tid*8;
  short* BL0 = &Bl[0][0] + tid*8;
  short* BL1 = &Bl[0][0] + 2048 + tid*8;

  for (int kt = 0; kt < 64; ++kt) {
    const int k0 = kt * 32;
    __syncthreads();
    gload16(Ap0 + k0, AL0);
    gload16(Ap1 + k0, AL1);
    gload16(Bp0 + k0, BL0);
    gload16(Bp1 + k0, BL1);
    __syncthreads();
    s16x8 af[4], bfr[4];
    #pragma unroll
    for (int mi=0; mi<4; ++mi) af[mi] = *(const s16x8*)&Al[wr*64 + mi*16 + l15][l4*8];
    #pragma unroll
    for (int ni=0; ni<4; ++ni) bfr[ni] = *(const s16x8*)&Bl[colmap(wc,ni) + l15][l4*8];
    #pragma unroll
    for (int mi=0; mi<4; ++mi)
      #pragma unroll
      for (int ni=0; ni<4; ++ni)
        acc[mi][ni] = __builtin_amdgcn_mfma_f32_16x16x32_bf16(af[mi], bfr[ni], acc[mi][ni], 0,0,0);
  }

  #pragma unroll
  for (int mi=0; mi<4; ++mi)
    #pragma unroll
    for (int r=0; r<4; ++r) {
      const int mrow = m0 + wr*64 + mi*16 + l4*4 + r;
      #pragma unroll
      for (int ni=0; ni<4; ++ni)
        out[(size_t)mrow*2048 + n0 + colmap(wc,ni) + l15] = acc[mi][ni][r];
    }
}

// ---------------- launch ----------------
extern "C" void kernel_launch(void* const* d_in, const int* in_sizes, int n_in,
                              void* d_out, int out_size, void* d_ws, size_t ws_size,
                              hipStream_t stream) {
  const float* hidden = (const float*)d_in[0];
  // d_in[1] attention_mask: exactly causal -> analytic
  const float* ropeC  = (const float*)d_in[2];
  const float* ropeS  = (const float*)d_in[3];
  const float* Wq     = (const float*)d_in[4];
  const float* Wk     = (const float*)d_in[5];
  const float* Wv     = (const float*)d_in[6];
  const float* Wo     = (const float*)d_in[7];
  float* out = (float*)d_out;
  char* ws = (char*)d_ws;

  short* hsb = (short*)(ws + 0);                 // 16,777,216
  short* WqT = (short*)(ws + 16777216);          //  8,388,608
  short* WkT = (short*)(ws + 25165824);          //    524,288
  short* WvT = (short*)(ws + 25690112);          //    524,288
  short* WoT = (short*)(ws + 26214400);          //  8,388,608
  short* Qb  = (short*)(ws + 34603008);          // 16,777,216
  short* Kb  = (short*)(ws + 51380224);          //  1,048,576
  short* Vb  = (short*)(ws + 52428800);          //  1,048,576
  short* Ob  = hsb;                              // alias (hsb dead after gemm_qkv)

  cvt_f32_bf16<<<dim3((NM*NHID/4 + 255)/256), dim3(256), 0, stream>>>(hidden, hsb, NM*NHID/4);
  cvtT<<<dim3(64,64), dim3(256), 0, stream>>>(Wq, WqT, 2048, 2048);
  cvtT<<<dim3(4, 64), dim3(256), 0, stream>>>(Wk, WkT, 2048, 128);
  cvtT<<<dim3(4, 64), dim3(256), 0, stream>>>(Wv, WvT, 2048, 128);
  cvtT<<<dim3(64,64), dim3(256), 0, stream>>>(Wo, WoT, 2048, 2048);

  gemm_qkv<<<dim3(NM/128, 18), dim3(256), 0, stream>>>(hsb, WqT, WkT, WvT, ropeC, ropeS, Qb, Kb, Vb);
  attn_fwd<<<dim3(16, NHEAD, NB), dim3(256), 0, stream>>>(Qb, Kb, Vb, Ob);
  gemm_out<<<dim3(NM/128, 2048/128), dim3(256), 0, stream>>>(Ob, WoT, out);
}